// Round 1
// 1016.446 us; speedup vs baseline: 1.1488x; 1.1488x over previous
//
#include <hip/hip_runtime.h>
#include <math.h>

// Problem constants: N=20000, E=160000, D=768, H=256, C=10
// Outputs (fp32, concatenated): logits [N,10], node_features [N,513], edge_pairs [E,1026]

typedef __attribute__((ext_vector_type(8))) short short8;
typedef __attribute__((ext_vector_type(4))) float f32x4;
typedef __attribute__((ext_vector_type(2))) float f32x2;

static __device__ __forceinline__ unsigned short f2bf(float f) {
    unsigned u = __float_as_uint(f);
    u += 0x7fffu + ((u >> 16) & 1u);  // RNE
    return (unsigned short)(u >> 16);
}
static __device__ __forceinline__ float bf2f(unsigned short h) {
    return __uint_as_float((unsigned)h << 16);
}

// ---------------- CSR build ----------------

__global__ void k_hist(const int* __restrict__ dst, int* __restrict__ deg,
                       int* __restrict__ rank, int e) {
    int i = blockIdx.x * blockDim.x + threadIdx.x;
    if (i < e) rank[i] = atomicAdd(&deg[dst[i]], 1);
}

__global__ void k_dinv(const int* __restrict__ deg, float* __restrict__ dinv, int n) {
    int i = blockIdx.x * blockDim.x + threadIdx.x;
    if (i < n) dinv[i] = 1.0f / sqrtf((float)(deg[i] + 1));  // +1 self-loop
}

// single-block scan, thread-coarsened: each thread owns a contiguous chunk.
__global__ __launch_bounds__(1024) void k_scan(const int* __restrict__ deg, int* __restrict__ off,
                                               int n, int total) {
    __shared__ int part[1024];
    const int t = threadIdx.x;
    const int per = (n + 1023) >> 10;
    const int s0 = t * per;
    int s1 = s0 + per; if (s1 > n) s1 = n;
    int s = 0;
    for (int i = s0; i < s1; i++) s += deg[i];
    part[t] = s;
    __syncthreads();
    int x = s;
    for (int ofs = 1; ofs < 1024; ofs <<= 1) {
        int add = (t >= ofs) ? part[t - ofs] : 0;
        __syncthreads();
        x += add;
        part[t] = x;
        __syncthreads();
    }
    int run = x - s;  // exclusive prefix of this chunk
    for (int i = s0; i < s1; i++) { off[i] = run; run += deg[i]; }
    if (t == 0) off[n] = total;
}

__global__ void k_scatter(const int* __restrict__ src, const int* __restrict__ dst,
                          const float* __restrict__ dinv, const int* __restrict__ off,
                          const int* __restrict__ rank, int* __restrict__ csr_src,
                          float* __restrict__ csr_w, int e) {
    int i = blockIdx.x * blockDim.x + threadIdx.x;
    if (i < e) {
        int d = dst[i], s = src[i];
        int pos = off[d] + rank[i];
        csr_src[pos] = s;
        csr_w[pos]   = dinv[s] * dinv[d];
    }
}

// ---------------- fp32 -> bf16 hi/lo split ----------------

__global__ void k_split_x(const float* __restrict__ x, unsigned short* __restrict__ hi,
                          unsigned short* __restrict__ lo, int total4) {
    const int stride = gridDim.x * blockDim.x;
    for (int i = blockIdx.x * blockDim.x + threadIdx.x; i < total4; i += stride) {
        const float4 v = ((const float4*)x)[i];
        const unsigned short h0 = f2bf(v.x), h1 = f2bf(v.y), h2 = f2bf(v.z), h3 = f2bf(v.w);
        const unsigned short l0 = f2bf(v.x - bf2f(h0)), l1 = f2bf(v.y - bf2f(h1)),
                             l2 = f2bf(v.z - bf2f(h2)), l3 = f2bf(v.w - bf2f(h3));
        *(ushort4*)(hi + 4 * (size_t)i) = make_ushort4(h0, h1, h2, h3);
        *(ushort4*)(lo + 4 * (size_t)i) = make_ushort4(l0, l1, l2, l3);
    }
}

// W [K,N] fp32 -> Wt [N,K] bf16 hi/lo (transposed so MFMA B-frags are contiguous-K)
__global__ void k_split_wt(const float* __restrict__ W, unsigned short* __restrict__ wthi,
                           unsigned short* __restrict__ wtlo, int K, int N) {
    int idx = blockIdx.x * blockDim.x + threadIdx.x;
    if (idx >= K * N) return;
    const int k = idx / N, nn = idx - k * N;
    const float v = W[idx];
    const unsigned short h = f2bf(v);
    wthi[(size_t)nn * K + k] = h;
    wtlo[(size_t)nn * K + k] = f2bf(v - bf2f(h));
}

// ---------------- split-bf16 MFMA GEMM: C[M,256] = (Ahi+Alo)[M,K] @ (Bhi+Blo)^T[K,256] ----------------
// BM=BN=128, BK=32, 256 threads (2x2 waves, each 64x64 via 4x4 16x16x32 fragments).
// 3-term split: hi*hi + hi*lo + lo*hi (lo*lo ~ 2^-18 rel, dropped).
// LDS tiles [128][32] bf16 with 16B-chunk XOR swizzle (chunk ^= (row>>1)&3) -> conflict-free b128 reads.
__global__ __launch_bounds__(256) void k_gemm_mfma(
    const unsigned short* __restrict__ Ahi, const unsigned short* __restrict__ Alo,
    const unsigned short* __restrict__ Bhi, const unsigned short* __restrict__ Blo,
    float* __restrict__ C, int M, int K)
{
    __shared__ short As_hi[128 * 32], As_lo[128 * 32], Bs_hi[128 * 32], Bs_lo[128 * 32];
    const int tid = threadIdx.x;
    const int m0 = blockIdx.y * 128, n0 = blockIdx.x * 128;
    const int lane = tid & 63;
    const int wr = (tid >> 7) & 1, wc = (tid >> 6) & 1;
    const int l15 = lane & 15, l16 = lane >> 4;

    f32x4 acc[4][4] = {};

    // staging: thread -> (row = tid>>1, two 16B chunks)
    const int srow = tid >> 1;
    const int sc0 = (tid & 1) * 2;
    const bool aok = (m0 + srow) < M;
    const unsigned short* Ap  = Ahi + (size_t)(m0 + srow) * K;
    const unsigned short* Alp = Alo + (size_t)(m0 + srow) * K;
    const unsigned short* Bp  = Bhi + (size_t)(n0 + srow) * K;
    const unsigned short* Blp = Blo + (size_t)(n0 + srow) * K;
    const int sw0 = ((sc0 ^ ((srow >> 1) & 3)) << 3);
    const int sw1 = (((sc0 + 1) ^ ((srow >> 1) & 3)) << 3);
    const int sbase = srow * 32;

    for (int k0 = 0; k0 < K; k0 += 32) {
        short8 ah0 = {0,0,0,0,0,0,0,0}, ah1 = {0,0,0,0,0,0,0,0};
        short8 al0 = {0,0,0,0,0,0,0,0}, al1 = {0,0,0,0,0,0,0,0};
        if (aok) {
            ah0 = *(const short8*)(Ap  + k0 + sc0 * 8);
            ah1 = *(const short8*)(Ap  + k0 + sc0 * 8 + 8);
            al0 = *(const short8*)(Alp + k0 + sc0 * 8);
            al1 = *(const short8*)(Alp + k0 + sc0 * 8 + 8);
        }
        const short8 bh0 = *(const short8*)(Bp  + k0 + sc0 * 8);
        const short8 bh1 = *(const short8*)(Bp  + k0 + sc0 * 8 + 8);
        const short8 bl0 = *(const short8*)(Blp + k0 + sc0 * 8);
        const short8 bl1 = *(const short8*)(Blp + k0 + sc0 * 8 + 8);
        __syncthreads();  // protect previous iteration's reads
        *(short8*)&As_hi[sbase + sw0] = ah0;
        *(short8*)&As_hi[sbase + sw1] = ah1;
        *(short8*)&As_lo[sbase + sw0] = al0;
        *(short8*)&As_lo[sbase + sw1] = al1;
        *(short8*)&Bs_hi[sbase + sw0] = bh0;
        *(short8*)&Bs_hi[sbase + sw1] = bh1;
        *(short8*)&Bs_lo[sbase + sw0] = bl0;
        *(short8*)&Bs_lo[sbase + sw1] = bl1;
        __syncthreads();

        short8 afh[4], afl[4];
#pragma unroll
        for (int i = 0; i < 4; i++) {
            const int r = wr * 64 + i * 16 + l15;
            const int off = r * 32 + ((l16 ^ ((r >> 1) & 3)) << 3);
            afh[i] = *(const short8*)&As_hi[off];
            afl[i] = *(const short8*)&As_lo[off];
        }
#pragma unroll
        for (int j = 0; j < 4; j++) {
            const int r = wc * 64 + j * 16 + l15;
            const int off = r * 32 + ((l16 ^ ((r >> 1) & 3)) << 3);
            const short8 bfh = *(const short8*)&Bs_hi[off];
            const short8 bfl = *(const short8*)&Bs_lo[off];
#pragma unroll
            for (int i = 0; i < 4; i++) {
                acc[i][j] = __builtin_amdgcn_mfma_f32_16x16x32_bf16(afh[i], bfh, acc[i][j], 0, 0, 0);
                acc[i][j] = __builtin_amdgcn_mfma_f32_16x16x32_bf16(afh[i], bfl, acc[i][j], 0, 0, 0);
                acc[i][j] = __builtin_amdgcn_mfma_f32_16x16x32_bf16(afl[i], bfh, acc[i][j], 0, 0, 0);
            }
        }
    }

    // C/D layout (verified m89/m91): col = lane&15, row = (lane>>4)*4 + q
#pragma unroll
    for (int i = 0; i < 4; i++) {
#pragma unroll
        for (int q = 0; q < 4; q++) {
            const int m = m0 + wr * 64 + i * 16 + l16 * 4 + q;
            if (m < M) {
#pragma unroll
                for (int j = 0; j < 4; j++)
                    C[(size_t)m * 256 + n0 + wc * 64 + j * 16 + l15] = acc[i][j][q];
            }
        }
    }
}

// ---------------- aggregation (dim=256): wave per node, float4 per lane ----------------
// h[v] = tanh(sum_nbr w*t[u] + dinv^2*t[v] + b); optional bf16 hi/lo split out (layer1),
// optional fused W2 row-dot -> sv (layer2).
__global__ __launch_bounds__(256) void k_aggregate(
    const float* __restrict__ t, const float* __restrict__ bias,
    const float* __restrict__ dinv, const int* __restrict__ off,
    const int* __restrict__ csr_src, const float* __restrict__ csr_w,
    float* __restrict__ nf, int col0,
    unsigned short* __restrict__ hhi, unsigned short* __restrict__ hlo,
    const float* __restrict__ W2, float* __restrict__ sv, int n)
{
    const int v = blockIdx.x * 4 + (threadIdx.x >> 6);
    if (v >= n) return;
    const int lane = threadIdx.x & 63;
    const float di = dinv[v];
    const float4 tb = *(const float4*)(bias + lane * 4);
    const float4 a  = *(const float4*)(t + (size_t)v * 256 + lane * 4);
    const float dii = di * di;
    float4 s4 = make_float4(dii * a.x, dii * a.y, dii * a.z, dii * a.w);
    const int e_ = off[v + 1];
    for (int idx = off[v]; idx < e_; idx++) {
        const int u = csr_src[idx];
        const float w = csr_w[idx];
        const float4 tv = *(const float4*)(t + (size_t)u * 256 + lane * 4);
        s4.x = fmaf(w, tv.x, s4.x);
        s4.y = fmaf(w, tv.y, s4.y);
        s4.z = fmaf(w, tv.z, s4.z);
        s4.w = fmaf(w, tv.w, s4.w);
    }
    float4 r;
    r.x = tanhf(s4.x + tb.x);
    r.y = tanhf(s4.y + tb.y);
    r.z = tanhf(s4.z + tb.z);
    r.w = tanhf(s4.w + tb.w);

    float* nfp = nf + (size_t)v * 513 + col0 + lane * 4;
    nfp[0] = r.x; nfp[1] = r.y; nfp[2] = r.z; nfp[3] = r.w;

    if (hhi) {  // split for next layer's MFMA GEMM
        const unsigned short h0 = f2bf(r.x), h1 = f2bf(r.y), h2 = f2bf(r.z), h3 = f2bf(r.w);
        const unsigned short l0 = f2bf(r.x - bf2f(h0)), l1 = f2bf(r.y - bf2f(h1)),
                             l2 = f2bf(r.z - bf2f(h2)), l3 = f2bf(r.w - bf2f(h3));
        *(ushort4*)(hhi + (size_t)v * 256 + lane * 4) = make_ushort4(h0, h1, h2, h3);
        *(ushort4*)(hlo + (size_t)v * 256 + lane * 4) = make_ushort4(l0, l1, l2, l3);
    }
    if (W2) {  // fused layer-3 row-dot: sv[v] = dot(h2[v,:], W2)
        const float4 w4 = *(const float4*)(W2 + lane * 4);
        float p = r.x * w4.x + r.y * w4.y + r.z * w4.z + r.w * w4.w;
        for (int ofs = 32; ofs > 0; ofs >>= 1) p += __shfl_down(p, ofs, 64);
        if (lane == 0) sv[v] = p;
    }
}

__global__ void k_agg_scalar(const float* __restrict__ s, const float* __restrict__ b2,
                             const float* __restrict__ dinv, const int* __restrict__ off,
                             const int* __restrict__ csr_src, const float* __restrict__ csr_w,
                             float* __restrict__ nf, int n) {
    const int v = blockIdx.x * blockDim.x + threadIdx.x;
    if (v >= n) return;
    const float di = dinv[v];
    float acc = di * di * s[v];
    const int e_ = off[v + 1];
    for (int idx = off[v]; idx < e_; idx++) acc += csr_w[idx] * s[csr_src[idx]];
    nf[(size_t)v * 513 + 512] = tanhf(acc + b2[0]);
}

// ---------------- classifier: logits[v] = nf[v] @ Wc + bc (wave per node) ----------------
__global__ __launch_bounds__(256) void k_classifier(const float* __restrict__ nf,
                                                    const float* __restrict__ Wc,
                                                    const float* __restrict__ bc,
                                                    float* __restrict__ logits, int n) {
    const int v = blockIdx.x * 4 + (threadIdx.x >> 6);
    const int lane = threadIdx.x & 63;
    if (v >= n) return;
    float p[10] = {};
    for (int k = lane; k < 513; k += 64) {
        const float x = nf[(size_t)v * 513 + k];
#pragma unroll
        for (int c = 0; c < 10; c++) p[c] += x * Wc[k * 10 + c];
    }
#pragma unroll
    for (int c = 0; c < 10; c++) {
        float q = p[c];
        for (int ofs = 32; ofs > 0; ofs >>= 1) q += __shfl_down(q, ofs, 64);
        if (lane == 0) logits[(size_t)v * 10 + c] = q + bc[c];
    }
}

// ---------------- edge pair gather: out[e] = [nf[src[e]], nf[dst[e]]] ----------------
// f32x2 nontemporal stores: pairs (656 MB) is a one-shot stream; keep it out of L2/L3
// so nf (41 MB) stays Infinity-Cache-resident for the gathers.
__global__ __launch_bounds__(256) void k_edge_pairs(const float* __restrict__ nf,
                                                    const int* __restrict__ src,
                                                    const int* __restrict__ dst,
                                                    float* __restrict__ out, int e) {
    const int eid = blockIdx.x;
    const int si = src[eid], ti = dst[eid];
    const float* __restrict__ srow = nf + (size_t)si * 513;
    const float* __restrict__ trow = nf + (size_t)ti * 513;
    float* __restrict__ orow = out + (size_t)eid * 1026;  // byte offset 4104*eid, 8B-aligned
    for (int j2 = threadIdx.x; j2 < 513; j2 += 256) {
        const int j = j2 * 2;
        const float a = (j < 513) ? srow[j] : trow[j - 513];
        const float b = (j + 1 < 513) ? srow[j + 1] : trow[j - 512];
        f32x2 val = {a, b};
        __builtin_nontemporal_store(val, (f32x2*)(orow + j));
    }
}

extern "C" void kernel_launch(void* const* d_in, const int* in_sizes, int n_in,
                              void* d_out, int out_size, void* d_ws, size_t ws_size,
                              hipStream_t stream) {
    const float* x  = (const float*)d_in[0];
    const int*   ei = (const int*)d_in[1];
    const float* W0 = (const float*)d_in[2];
    const float* b0 = (const float*)d_in[3];
    const float* W1 = (const float*)d_in[4];
    const float* b1 = (const float*)d_in[5];
    const float* W2 = (const float*)d_in[6];
    const float* b2 = (const float*)d_in[7];
    const float* Wc = (const float*)d_in[8];
    const float* bc = (const float*)d_in[9];

    const int n = in_sizes[0] / 768;   // 20000
    const int e = in_sizes[1] / 2;     // 160000
    const int* src  = ei;
    const int* dstp = ei + e;

    float* out    = (float*)d_out;
    float* logits = out;
    float* nf     = out + (size_t)n * 10;
    float* pairs  = nf + (size_t)n * 513;

    char* w = (char*)d_ws;
    auto alloc = [&](size_t bytes) { char* p = w; w += (bytes + 255) & ~(size_t)255; return p; };
    int*   deg     = (int*)alloc((size_t)n * 4);
    int*   off     = (int*)alloc((size_t)(n + 1) * 4);
    int*   rank    = (int*)alloc((size_t)e * 4);
    int*   csr_src = (int*)alloc((size_t)e * 4);
    float* csr_w   = (float*)alloc((size_t)e * 4);
    float* dinv    = (float*)alloc((size_t)n * 4);
    unsigned short* xhi   = (unsigned short*)alloc((size_t)n * 768 * 2);
    unsigned short* xlo   = (unsigned short*)alloc((size_t)n * 768 * 2);
    unsigned short* w0thi = (unsigned short*)alloc((size_t)256 * 768 * 2);
    unsigned short* w0tlo = (unsigned short*)alloc((size_t)256 * 768 * 2);
    unsigned short* w1thi = (unsigned short*)alloc((size_t)256 * 256 * 2);
    unsigned short* w1tlo = (unsigned short*)alloc((size_t)256 * 256 * 2);
    float* t  = (float*)alloc((size_t)n * 256 * 4);
    unsigned short* hhi = (unsigned short*)alloc((size_t)n * 256 * 2);
    unsigned short* hlo = (unsigned short*)alloc((size_t)n * 256 * 2);
    float* sv = (float*)alloc((size_t)n * 4);

    hipMemsetAsync(deg, 0, (size_t)n * 4, stream);

    // CSR build (rank recorded in hist pass; no cursor atomics)
    k_hist<<<(e + 255) / 256, 256, 0, stream>>>(dstp, deg, rank, e);
    k_dinv<<<(n + 255) / 256, 256, 0, stream>>>(deg, dinv, n);
    k_scan<<<1, 1024, 0, stream>>>(deg, off, n, e);
    k_scatter<<<(e + 255) / 256, 256, 0, stream>>>(src, dstp, dinv, off, rank, csr_src, csr_w, e);

    // bf16 hi/lo splits for MFMA
    k_split_x<<<2048, 256, 0, stream>>>(x, xhi, xlo, n * 768 / 4);
    k_split_wt<<<(768 * 256 + 255) / 256, 256, 0, stream>>>(W0, w0thi, w0tlo, 768, 256);
    k_split_wt<<<(256 * 256 + 255) / 256, 256, 0, stream>>>(W1, w1thi, w1tlo, 256, 256);

    const int mb = (n + 127) / 128;

    // layer 1: t = x @ W0 (split-bf16 MFMA); h1 = tanh(agg(t)+b0), also emit h1 hi/lo
    k_gemm_mfma<<<dim3(2, mb), 256, 0, stream>>>(xhi, xlo, w0thi, w0tlo, t, n, 768);
    k_aggregate<<<(n + 3) / 4, 256, 0, stream>>>(t, b0, dinv, off, csr_src, csr_w,
                                                 nf, 0, hhi, hlo, nullptr, nullptr, n);

    // layer 2: t = h1 @ W1; h2 = tanh(agg(t)+b1), fused sv = h2 @ W2
    k_gemm_mfma<<<dim3(2, mb), 256, 0, stream>>>(hhi, hlo, w1thi, w1tlo, t, n, 256);
    k_aggregate<<<(n + 3) / 4, 256, 0, stream>>>(t, b1, dinv, off, csr_src, csr_w,
                                                 nf, 256, nullptr, nullptr, W2, sv, n);

    // layer 3 scalar aggregate -> nf col 512
    k_agg_scalar<<<(n + 255) / 256, 256, 0, stream>>>(sv, b2, dinv, off, csr_src, csr_w, nf, n);

    // classifier (reads full nf incl. col 512)
    k_classifier<<<(n + 3) / 4, 256, 0, stream>>>(nf, Wc, bc, logits, n);

    // edge pair features
    k_edge_pairs<<<e, 256, 0, stream>>>(nf, src, dstp, pairs, e);
}